// Round 24
// baseline (713.775 us; speedup 1.0000x reference)
//
#include <hip/hip_runtime.h>

#define NN 100000
#define DD 128
#define EE 600000
#define BINSZ 8192   // nodes per partition bin (2^13)
#define NBIN 13      // ceil(NN / BINSZ)
#define SPAN 1024    // edges owned per wave in part_kernel
#define WPR 586      // ceil(EE / SPAN) waves per relation
#define CAP 192      // per-(rel,wave,bin) segment capacity (mean 84 + 12 sigma)
#define RCAP 76800   // csr ints per (rel,parent) region

typedef __attribute__((ext_vector_type(8))) short short8;   // 8 x bf16 bits
typedef __attribute__((ext_vector_type(4))) float f32x4;
typedef __attribute__((ext_vector_type(4))) unsigned int u32x4;

// relations: M_M, M_E, M_S, E_S, E_M, S_M, S_E, S_S, E_E  (M=0, E=1, S=2)
__device__ const int D_SRC[9]  = {0, 0, 0, 1, 1, 2, 2, 2, 1};
__device__ const int D_RELS[3][3] = {{0, 4, 5}, {1, 6, 8}, {2, 3, 7}};  // by dst

__device__ inline unsigned short f2bf(float f) {
    unsigned u = __float_as_uint(f);
    u = (u + 0x7fffu + ((u >> 16) & 1u)) >> 16;   // RNE
    return (unsigned short)u;
}
__device__ inline int mbcnt64(unsigned long long m) {
    return __builtin_amdgcn_mbcnt_hi((unsigned)(m >> 32),
           __builtin_amdgcn_mbcnt_lo((unsigned)m, 0));
}

// ---------------------------------------------------------------------------
// x (f32) -> bf16 table, 8 elems/thread. NT loads: x is single-use.
__global__ __launch_bounds__(256) void xbf_kernel(const float* __restrict__ x,
                                                  unsigned short* __restrict__ xb) {
    int i = blockIdx.x * 256 + threadIdx.x;
    if (i < 3 * NN * DD / 8) {
        const f32x4* p = reinterpret_cast<const f32x4*>(x) + (size_t)i * 2;
        f32x4 a = __builtin_nontemporal_load(p);
        f32x4 c = __builtin_nontemporal_load(p + 1);
        ushort4 o0, o1;
        o0.x = f2bf(a[0]); o0.y = f2bf(a[1]); o0.z = f2bf(a[2]); o0.w = f2bf(a[3]);
        o1.x = f2bf(c[0]); o1.y = f2bf(c[1]); o1.z = f2bf(c[2]); o1.w = f2bf(c[3]);
        reinterpret_cast<ushort4*>(xb)[(size_t)i * 2] = o0;
        reinterpret_cast<ushort4*>(xb)[(size_t)i * 2 + 1] = o1;
    }
}

// ---------------------------------------------------------------------------
// Wt[r][n][k] = bf16(W[r][k][n]); bsum[dt][n] = sum of the 3 relation biases.
__global__ __launch_bounds__(256) void prep_kernel(const float* __restrict__ W,
                                                   const float* __restrict__ b,
                                                   unsigned short* __restrict__ Wt,
                                                   float* __restrict__ bsum) {
    int t = blockIdx.x * 256 + threadIdx.x;
    if (t < 9 * 128 * 128) {
        int r = t >> 14, n = (t >> 7) & 127, k = t & 127;
        Wt[t] = f2bf(W[r * 16384 + k * 128 + n]);
    }
    if (t < 384) {
        int dt = t >> 7, col = t & 127;
        const int R0[3] = {0, 1, 2}, R1[3] = {4, 6, 3}, R2[3] = {5, 8, 7};
        bsum[t] = b[R0[dt] * 128 + col] + b[R1[dt] * 128 + col] + b[R2[dt] * 128 + col];
    }
}

// ---------------------------------------------------------------------------
// P1 (r16-proven): 1-pass wave-ballot radix partition; d-side packed:
// s (17 bits) | (d & 8191) << 17. No LDS, no atomics.
__global__ __launch_bounds__(256) void part_kernel(const int* __restrict__ src,
                                                   const int* __restrict__ dst,
                                                   int* __restrict__ dbin,
                                                   int* __restrict__ sbin,
                                                   int* __restrict__ dn,
                                                   int* __restrict__ sn) {
    const int rel = blockIdx.y;
    const int wid = blockIdx.x * 4 + (threadIdx.x >> 6);
    if (wid >= WPR) return;
    const int lane = threadIdx.x & 63;
    const int* s_arr = src + (size_t)rel * EE;
    const int* d_arr = dst + (size_t)rel * EE;
    const int base = wid * SPAN;
    const size_t wbase = ((size_t)rel * WPR + wid) * NBIN;

    int curD[NBIN], curS[NBIN];
#pragma unroll
    for (int b = 0; b < NBIN; ++b) { curD[b] = 0; curS[b] = 0; }

    for (int i0 = 0; i0 < SPAN; i0 += 64) {
        int i = base + i0 + lane;
        bool valid = (i < EE);
        int s = valid ? s_arr[i] : 0;
        int d = valid ? d_arr[i] : 0;
        int db = valid ? (d >> 13) : -1;
        int sb = valid ? (s >> 13) : -1;
        int packed = s | ((d & 8191) << 17);
#pragma unroll
        for (int b = 0; b < NBIN; ++b) {
            unsigned long long m = __ballot(db == b);
            if (m) {
                int off = mbcnt64(m);
                if (db == b) dbin[(wbase + b) * CAP + curD[b] + off] = packed;
                curD[b] += __popcll(m);
            }
            unsigned long long m2 = __ballot(sb == b);
            if (m2) {
                int off2 = mbcnt64(m2);
                if (sb == b) sbin[(wbase + b) * CAP + curS[b] + off2] = s;
                curS[b] += __popcll(m2);
            }
        }
    }
#pragma unroll
    for (int b = 0; b < NBIN; ++b) {
        if (lane == b) { dn[wbase + b] = curD[b]; sn[wbase + b] = curS[b]; }
    }
}

// ---------------------------------------------------------------------------
// P2-d (r17-proven): one block per (parent-bin, rel); 8192-node LDS histogram
// -> 4-aligned scan -> direct scatter into compact L2-resident csr region.
__global__ __launch_bounds__(1024) void place_d_kernel(const int* __restrict__ dbin,
                                                       const int* __restrict__ dn,
                                                       int* __restrict__ csr,
                                                       int* __restrict__ row_start,
                                                       int* __restrict__ cnt_d) {
    __shared__ int h[BINSZ];      // 32 KB counts -> cursors
    __shared__ int sdata[1024];   // 4 KB scan
    const int parent = blockIdx.x, rel = blockIdx.y, t = threadIdx.x;
    const int d0 = parent * BINSZ;
    const int g = t >> 6, lane = t & 63;
    for (int i = t; i < BINSZ; i += 1024) h[i] = 0;
    __syncthreads();
    // pass 1: count
    for (int w = g; w < WPR; w += 16) {
        size_t rb = ((size_t)rel * WPR + w) * NBIN + parent;
        int n = dn[rb];
        const int* in = dbin + rb * CAP;
        for (int k = lane; k < n; k += 64)
            atomicAdd(&h[(unsigned)in[k] >> 17], 1);
    }
    __syncthreads();
    // 4-aligned exclusive prefix scan, 8 nodes/thread
    int c[8], p[8], sum = 0;
#pragma unroll
    for (int j = 0; j < 8; ++j) {
        c[j] = h[t * 8 + j];
        p[j] = (c[j] + 3) & ~3;
        sum += p[j];
    }
    sdata[t] = sum;
    __syncthreads();
    for (int dstep = 1; dstep < 1024; dstep <<= 1) {
        int v = (t >= dstep) ? sdata[t - dstep] : 0;
        __syncthreads();
        sdata[t] += v;
        __syncthreads();
    }
    int run = sdata[t] - sum;
    const int regionbase = (rel * NBIN + parent) * RCAP;
    int curj[8];
#pragma unroll
    for (int j = 0; j < 8; ++j) {
        int node = d0 + t * 8 + j;
        if (node < NN) {
            cnt_d[(size_t)rel * NN + node] = c[j];
            row_start[(size_t)rel * NN + node] = regionbase + run;
        }
        curj[j] = run;
        run += p[j];
    }
    __syncthreads();
#pragma unroll
    for (int j = 0; j < 8; ++j) h[t * 8 + j] = curj[j];
    __syncthreads();
    // pass 2: scatter into L2-resident compact region
    int* reg = csr + regionbase;
    for (int w = g; w < WPR; w += 16) {
        size_t rb = ((size_t)rel * WPR + w) * NBIN + parent;
        int n = dn[rb];
        const int* in = dbin + rb * CAP;
        for (int k = lane; k < n; k += 64) {
            int e = in[k];
            int pos = atomicAdd(&h[(unsigned)e >> 17], 1);   // LDS atomic
            reg[pos] = e & 0x1FFFF;
        }
    }
}

// ---------------------------------------------------------------------------
// P2-s: out-degree histogram -> rsqrt table, one block per (parent, rel).
__global__ __launch_bounds__(1024) void place_s_kernel(const int* __restrict__ sbin,
                                                       const int* __restrict__ sn,
                                                       float* __restrict__ rns_s) {
    __shared__ int h[BINSZ];
    const int parent = blockIdx.x, rel = blockIdx.y, t = threadIdx.x;
    const int d0 = parent * BINSZ;
    const int nvalid = min(BINSZ, NN - d0);
    const int g = t >> 6, lane = t & 63;
    for (int i = t; i < BINSZ; i += 1024) h[i] = 0;
    __syncthreads();
    for (int w = g; w < WPR; w += 16) {
        size_t rb = ((size_t)rel * WPR + w) * NBIN + parent;
        int n = sn[rb];
        const int* in = sbin + rb * CAP;
        for (int k = lane; k < n; k += 64)
            atomicAdd(&h[in[k] - d0], 1);
    }
    __syncthreads();
    float* rs = rns_s + (size_t)rel * NN + d0;
    for (int i = t; i < nvalid; i += 1024)
        rs[i] = rsqrtf(fmaxf((float)h[i], 1.0f));
}

// ---------------------------------------------------------------------------
// Gather, all dst types merged (blockIdx.y = slot, blockIdx.z = dt) — r20
// proven config. 16 lanes x 16B per row; 8-deep edge batch; NT agg3 stores
// keep the 230MB write stream out of L3 (xb stays resident).
__global__ __launch_bounds__(256) void gather_kernel(const unsigned short* __restrict__ xb,
                                                     const int* __restrict__ csr,
                                                     const int* __restrict__ row_start,
                                                     const int* __restrict__ cnt_d,
                                                     const float* __restrict__ rns_s,
                                                     unsigned short* __restrict__ agg3) {
    const int slot = blockIdx.y;
    const int dt = blockIdx.z;
    const int rel = D_RELS[dt][slot];
    const unsigned short* x = xb + (size_t)D_SRC[rel] * NN * DD;
    const float* rs = rns_s + (size_t)rel * NN;

    int t = blockIdx.x * 256 + threadIdx.x;
    int node = t >> 4, lane = t & 15;
    if (node >= NN) return;
    int c = cnt_d[(size_t)rel * NN + node];
    const int4* bp4 = reinterpret_cast<const int4*>(csr + row_start[(size_t)rel * NN + node]);

    float acc[8];
#pragma unroll
    for (int j = 0; j < 8; ++j) acc[j] = 0.f;

    for (int e0 = 0; e0 < c; e0 += 8) {
        int4 b0 = bp4[e0 >> 2];
        int4 b1 = bp4[(e0 >> 2) + 1];
        int si[8] = {b0.x, b0.y, b0.z, b0.w, b1.x, b1.y, b1.z, b1.w};
        float ns[8];
        uint4 v[8];
#pragma unroll
        for (int u = 0; u < 8; ++u) {
            bool ok = (e0 + u < c);
            int s = ok ? si[u] : si[0];          // si[0] valid: loop entered => c > e0
            ns[u] = ok ? rs[s] : 0.0f;
            v[u] = *reinterpret_cast<const uint4*>(x + (size_t)s * DD + lane * 8);
        }
#pragma unroll
        for (int u = 0; u < 8; ++u) {
            float n = ns[u];
            unsigned w0 = v[u].x, w1 = v[u].y, w2 = v[u].z, w3 = v[u].w;
            acc[0] += __uint_as_float(w0 << 16) * n;
            acc[1] += __uint_as_float(w0 & 0xffff0000u) * n;
            acc[2] += __uint_as_float(w1 << 16) * n;
            acc[3] += __uint_as_float(w1 & 0xffff0000u) * n;
            acc[4] += __uint_as_float(w2 << 16) * n;
            acc[5] += __uint_as_float(w2 & 0xffff0000u) * n;
            acc[6] += __uint_as_float(w3 << 16) * n;
            acc[7] += __uint_as_float(w3 & 0xffff0000u) * n;
        }
    }
    float nd = rsqrtf(fmaxf((float)c, 1.0f));
    u32x4 o;
    o[0] = (unsigned)f2bf(acc[0] * nd) | ((unsigned)f2bf(acc[1] * nd) << 16);
    o[1] = (unsigned)f2bf(acc[2] * nd) | ((unsigned)f2bf(acc[3] * nd) << 16);
    o[2] = (unsigned)f2bf(acc[4] * nd) | ((unsigned)f2bf(acc[5] * nd) << 16);
    o[3] = (unsigned)f2bf(acc[6] * nd) | ((unsigned)f2bf(acc[7] * nd) << 16);
    __builtin_nontemporal_store(o, reinterpret_cast<u32x4*>(
        agg3 + ((size_t)dt * NN + node) * 384 + slot * 128 + lane * 8));
}

// ---------------------------------------------------------------------------
// Fused GEMM, all 3 dst types (blockIdx.y = dt). FULLY BARRIER-FREE:
// A fragments direct from row-major agg3 (== fragment layout); B fragments
// direct from Wt (96KB per dt, L1/L2-resident). No LDS, no __syncthreads --
// waves pipeline the whole 6-chunk loop independently.
__global__ __launch_bounds__(256) void gemm_kernel(const unsigned short* __restrict__ agg3,
                                                   const unsigned short* __restrict__ Wt,
                                                   const float* __restrict__ bsum,
                                                   float* __restrict__ out) {
    const int t = threadIdx.x;
    const int w = t >> 6;            // wave 0..3 -> rows w*32..+31
    const int lane = t & 63;
    const int row0 = blockIdx.x * 128;
    const int dt = blockIdx.y;
    const unsigned short* agg = agg3 + (size_t)dt * NN * 384;
    const int* rels = D_RELS[dt];

    // per-thread A fragment base pointers (rows clamped: OOB rows compute
    // garbage but are never stored by the guarded epilogue)
    const int ar0 = min(row0 + w * 32 + (lane & 15), NN - 1);
    const int ar1 = min(row0 + w * 32 + 16 + (lane & 15), NN - 1);
    const unsigned short* ap0 = agg + (size_t)ar0 * 384 + (lane >> 4) * 8;
    const unsigned short* ap1 = agg + (size_t)ar1 * 384 + (lane >> 4) * 8;
    // per-thread B fragment base: row (lane&15)+cg*16, k-seg (lane>>4)*8
    const unsigned short* wb0 = Wt + (size_t)(lane & 15) * 128 + (lane >> 4) * 8;

    f32x4 acc[2][8];
#pragma unroll
    for (int rg = 0; rg < 2; ++rg)
#pragma unroll
        for (int cg = 0; cg < 8; ++cg) acc[rg][cg] = (f32x4){0.f, 0.f, 0.f, 0.f};

#pragma unroll
    for (int c = 0; c < 6; ++c) {           // K chunks of 64
        const unsigned short* wb = wb0 + (size_t)rels[c >> 1] * 16384 + (c & 1) * 64;
#pragma unroll
        for (int ks = 0; ks < 2; ++ks) {
            short8 a0 = *reinterpret_cast<const short8*>(ap0 + c * 64 + ks * 32);
            short8 a1 = *reinterpret_cast<const short8*>(ap1 + c * 64 + ks * 32);
#pragma unroll
            for (int cg = 0; cg < 8; ++cg) {
                short8 bfr = *reinterpret_cast<const short8*>(
                    wb + (size_t)cg * 16 * 128 + ks * 32);
                acc[0][cg] = __builtin_amdgcn_mfma_f32_16x16x32_bf16(a0, bfr, acc[0][cg], 0, 0, 0);
                acc[1][cg] = __builtin_amdgcn_mfma_f32_16x16x32_bf16(a1, bfr, acc[1][cg], 0, 0, 0);
            }
        }
    }
    // epilogue: bias + ReLU, regular stores
    const int col = lane & 15;
    float* o = out + (size_t)dt * NN * DD;
#pragma unroll
    for (int rg = 0; rg < 2; ++rg) {
        const int rbase = row0 + w * 32 + rg * 16 + (lane >> 4) * 4;
#pragma unroll
        for (int cg = 0; cg < 8; ++cg) {
            float bs = bsum[dt * 128 + cg * 16 + col];
#pragma unroll
            for (int j = 0; j < 4; ++j) {
                int grow = rbase + j;
                if (grow < NN)
                    o[(size_t)grow * DD + cg * 16 + col] = fmaxf(acc[rg][cg][j] + bs, 0.f);
            }
        }
    }
}

// ---------------------------------------------------------------------------
extern "C" void kernel_launch(void* const* d_in, const int* in_sizes, int n_in,
                              void* d_out, int out_size, void* d_ws, size_t ws_size,
                              hipStream_t stream) {
    const float* x   = (const float*)d_in[0];   // [3, N, D]
    const float* W   = (const float*)d_in[1];   // [9, D, D]
    const float* b   = (const float*)d_in[2];   // [9, D]
    const int*   src = (const int*)d_in[3];     // [9, E]
    const int*   dst = (const int*)d_in[4];     // [9, E]
    float* out = (float*)d_out;                 // [3, N, D]

    // workspace layout (~460 MB of ~614 MB); every consumed region is fully
    // rewritten each call -> no memsets needed.
    unsigned short* xb   = (unsigned short*)d_ws;            // 3*NN*DD bf16   (76.8 MB)
    unsigned short* agg3 = xb + (size_t)3 * NN * DD;         // 3*NN*384 bf16  (230.4 MB)
    int*   csr    = (int*)(agg3 + (size_t)3 * NN * 384);     // 9*NBIN*RCAP int (35.9 MB)
    int*   row_start = csr + (size_t)9 * NBIN * RCAP;        // 9*NN int
    int*   cnt_d  = row_start + (size_t)9 * NN;              // 9*NN int
    float* rns_s  = (float*)(cnt_d + (size_t)9 * NN);        // 9*NN f32
    unsigned short* Wt = (unsigned short*)(rns_s + (size_t)9 * NN); // 9*16384 bf16
    float* bsum = (float*)(Wt + 9 * 16384);                  // 384 f32
    int*   dbin = (int*)(bsum + 384);                        // 9*WPR*NBIN*CAP int (52.6 MB)
    int*   sbin = dbin + (size_t)9 * WPR * NBIN * CAP;       // 9*WPR*NBIN*CAP int (52.6 MB)
    int*   dn   = sbin + (size_t)9 * WPR * NBIN * CAP;       // 9*WPR*NBIN int
    int*   sn   = dn + 9 * WPR * NBIN;                       // 9*WPR*NBIN int

    prep_kernel<<<(9 * 16384 + 255) / 256, 256, 0, stream>>>(W, b, Wt, bsum);
    part_kernel<<<dim3((WPR + 3) / 4, 9), 256, 0, stream>>>(src, dst, dbin, sbin, dn, sn);
    place_d_kernel<<<dim3(NBIN, 9), 1024, 0, stream>>>(dbin, dn, csr, row_start, cnt_d);
    place_s_kernel<<<dim3(NBIN, 9), 1024, 0, stream>>>(sbin, sn, rns_s);

    // xbf right before gather: xb enters gather L3-hot.
    xbf_kernel<<<(3 * NN * DD / 8 + 255) / 256, 256, 0, stream>>>(x, xb);

    dim3 gg((NN * 16 + 255) / 256, 3, 3);
    gather_kernel<<<gg, 256, 0, stream>>>(xb, csr, row_start, cnt_d, rns_s, agg3);

    dim3 mg((NN + 127) / 128, 3);
    gemm_kernel<<<mg, 256, 0, stream>>>(agg3, Wt, bsum, out);
}

// Round 25
// 635.143 us; speedup vs baseline: 1.1238x; 1.1238x over previous
//
#include <hip/hip_runtime.h>

#define NN 100000
#define DD 128
#define EE 600000
#define BINSZ 8192   // nodes per partition bin (2^13)
#define NBIN 13      // ceil(NN / BINSZ)
#define SPAN 1024    // edges owned per wave in part_kernel
#define WPR 586      // ceil(EE / SPAN) waves per relation
#define CAP 192      // per-(rel,wave,bin) segment capacity (mean 84 + 12 sigma)
#define RCAP 76800   // csr ints per (rel,parent) region

typedef __attribute__((ext_vector_type(8))) short short8;   // 8 x bf16 bits
typedef __attribute__((ext_vector_type(4))) float f32x4;
typedef __attribute__((ext_vector_type(4))) unsigned int u32x4;

// relations: M_M, M_E, M_S, E_S, E_M, S_M, S_E, S_S, E_E  (M=0, E=1, S=2)
__device__ const int D_SRC[9]  = {0, 0, 0, 1, 1, 2, 2, 2, 1};
__device__ const int D_RELS[3][3] = {{0, 4, 5}, {1, 6, 8}, {2, 3, 7}};  // by dst

__device__ inline unsigned short f2bf(float f) {
    unsigned u = __float_as_uint(f);
    u = (u + 0x7fffu + ((u >> 16) & 1u)) >> 16;   // RNE
    return (unsigned short)u;
}
__device__ inline int mbcnt64(unsigned long long m) {
    return __builtin_amdgcn_mbcnt_hi((unsigned)(m >> 32),
           __builtin_amdgcn_mbcnt_lo((unsigned)m, 0));
}

// ---------------------------------------------------------------------------
// x (f32) -> bf16 table, 8 elems/thread. NT loads: x is single-use.
__global__ __launch_bounds__(256) void xbf_kernel(const float* __restrict__ x,
                                                  unsigned short* __restrict__ xb) {
    int i = blockIdx.x * 256 + threadIdx.x;
    if (i < 3 * NN * DD / 8) {
        const f32x4* p = reinterpret_cast<const f32x4*>(x) + (size_t)i * 2;
        f32x4 a = __builtin_nontemporal_load(p);
        f32x4 c = __builtin_nontemporal_load(p + 1);
        ushort4 o0, o1;
        o0.x = f2bf(a[0]); o0.y = f2bf(a[1]); o0.z = f2bf(a[2]); o0.w = f2bf(a[3]);
        o1.x = f2bf(c[0]); o1.y = f2bf(c[1]); o1.z = f2bf(c[2]); o1.w = f2bf(c[3]);
        reinterpret_cast<ushort4*>(xb)[(size_t)i * 2] = o0;
        reinterpret_cast<ushort4*>(xb)[(size_t)i * 2 + 1] = o1;
    }
}

// ---------------------------------------------------------------------------
// Wt[r][n][k] = bf16(W[r][k][n]); bsum[dt][n] = sum of the 3 relation biases.
__global__ __launch_bounds__(256) void prep_kernel(const float* __restrict__ W,
                                                   const float* __restrict__ b,
                                                   unsigned short* __restrict__ Wt,
                                                   float* __restrict__ bsum) {
    int t = blockIdx.x * 256 + threadIdx.x;
    if (t < 9 * 128 * 128) {
        int r = t >> 14, n = (t >> 7) & 127, k = t & 127;
        Wt[t] = f2bf(W[r * 16384 + k * 128 + n]);
    }
    if (t < 384) {
        int dt = t >> 7, col = t & 127;
        const int R0[3] = {0, 1, 2}, R1[3] = {4, 6, 3}, R2[3] = {5, 8, 7};
        bsum[t] = b[R0[dt] * 128 + col] + b[R1[dt] * 128 + col] + b[R2[dt] * 128 + col];
    }
}

// ---------------------------------------------------------------------------
// P1 (r16-proven): 1-pass wave-ballot radix partition; d-side packed:
// s (17 bits) | (d & 8191) << 17. No LDS, no atomics.
__global__ __launch_bounds__(256) void part_kernel(const int* __restrict__ src,
                                                   const int* __restrict__ dst,
                                                   int* __restrict__ dbin,
                                                   int* __restrict__ sbin,
                                                   int* __restrict__ dn,
                                                   int* __restrict__ sn) {
    const int rel = blockIdx.y;
    const int wid = blockIdx.x * 4 + (threadIdx.x >> 6);
    if (wid >= WPR) return;
    const int lane = threadIdx.x & 63;
    const int* s_arr = src + (size_t)rel * EE;
    const int* d_arr = dst + (size_t)rel * EE;
    const int base = wid * SPAN;
    const size_t wbase = ((size_t)rel * WPR + wid) * NBIN;

    int curD[NBIN], curS[NBIN];
#pragma unroll
    for (int b = 0; b < NBIN; ++b) { curD[b] = 0; curS[b] = 0; }

    for (int i0 = 0; i0 < SPAN; i0 += 64) {
        int i = base + i0 + lane;
        bool valid = (i < EE);
        int s = valid ? s_arr[i] : 0;
        int d = valid ? d_arr[i] : 0;
        int db = valid ? (d >> 13) : -1;
        int sb = valid ? (s >> 13) : -1;
        int packed = s | ((d & 8191) << 17);
#pragma unroll
        for (int b = 0; b < NBIN; ++b) {
            unsigned long long m = __ballot(db == b);
            if (m) {
                int off = mbcnt64(m);
                if (db == b) dbin[(wbase + b) * CAP + curD[b] + off] = packed;
                curD[b] += __popcll(m);
            }
            unsigned long long m2 = __ballot(sb == b);
            if (m2) {
                int off2 = mbcnt64(m2);
                if (sb == b) sbin[(wbase + b) * CAP + curS[b] + off2] = s;
                curS[b] += __popcll(m2);
            }
        }
    }
#pragma unroll
    for (int b = 0; b < NBIN; ++b) {
        if (lane == b) { dn[wbase + b] = curD[b]; sn[wbase + b] = curS[b]; }
    }
}

// ---------------------------------------------------------------------------
// P2-d (r17-proven): one block per (parent-bin, rel); 8192-node LDS histogram
// -> 4-aligned scan -> direct scatter into compact L2-resident csr region.
__global__ __launch_bounds__(1024) void place_d_kernel(const int* __restrict__ dbin,
                                                       const int* __restrict__ dn,
                                                       int* __restrict__ csr,
                                                       int* __restrict__ row_start,
                                                       int* __restrict__ cnt_d) {
    __shared__ int h[BINSZ];      // 32 KB counts -> cursors
    __shared__ int sdata[1024];   // 4 KB scan
    const int parent = blockIdx.x, rel = blockIdx.y, t = threadIdx.x;
    const int d0 = parent * BINSZ;
    const int g = t >> 6, lane = t & 63;
    for (int i = t; i < BINSZ; i += 1024) h[i] = 0;
    __syncthreads();
    // pass 1: count
    for (int w = g; w < WPR; w += 16) {
        size_t rb = ((size_t)rel * WPR + w) * NBIN + parent;
        int n = dn[rb];
        const int* in = dbin + rb * CAP;
        for (int k = lane; k < n; k += 64)
            atomicAdd(&h[(unsigned)in[k] >> 17], 1);
    }
    __syncthreads();
    // 4-aligned exclusive prefix scan, 8 nodes/thread
    int c[8], p[8], sum = 0;
#pragma unroll
    for (int j = 0; j < 8; ++j) {
        c[j] = h[t * 8 + j];
        p[j] = (c[j] + 3) & ~3;
        sum += p[j];
    }
    sdata[t] = sum;
    __syncthreads();
    for (int dstep = 1; dstep < 1024; dstep <<= 1) {
        int v = (t >= dstep) ? sdata[t - dstep] : 0;
        __syncthreads();
        sdata[t] += v;
        __syncthreads();
    }
    int run = sdata[t] - sum;
    const int regionbase = (rel * NBIN + parent) * RCAP;
    int curj[8];
#pragma unroll
    for (int j = 0; j < 8; ++j) {
        int node = d0 + t * 8 + j;
        if (node < NN) {
            cnt_d[(size_t)rel * NN + node] = c[j];
            row_start[(size_t)rel * NN + node] = regionbase + run;
        }
        curj[j] = run;
        run += p[j];
    }
    __syncthreads();
#pragma unroll
    for (int j = 0; j < 8; ++j) h[t * 8 + j] = curj[j];
    __syncthreads();
    // pass 2: scatter into L2-resident compact region
    int* reg = csr + regionbase;
    for (int w = g; w < WPR; w += 16) {
        size_t rb = ((size_t)rel * WPR + w) * NBIN + parent;
        int n = dn[rb];
        const int* in = dbin + rb * CAP;
        for (int k = lane; k < n; k += 64) {
            int e = in[k];
            int pos = atomicAdd(&h[(unsigned)e >> 17], 1);   // LDS atomic
            reg[pos] = e & 0x1FFFF;
        }
    }
}

// ---------------------------------------------------------------------------
// P2-s: out-degree histogram -> rsqrt table, one block per (parent, rel).
__global__ __launch_bounds__(1024) void place_s_kernel(const int* __restrict__ sbin,
                                                       const int* __restrict__ sn,
                                                       float* __restrict__ rns_s) {
    __shared__ int h[BINSZ];
    const int parent = blockIdx.x, rel = blockIdx.y, t = threadIdx.x;
    const int d0 = parent * BINSZ;
    const int nvalid = min(BINSZ, NN - d0);
    const int g = t >> 6, lane = t & 63;
    for (int i = t; i < BINSZ; i += 1024) h[i] = 0;
    __syncthreads();
    for (int w = g; w < WPR; w += 16) {
        size_t rb = ((size_t)rel * WPR + w) * NBIN + parent;
        int n = sn[rb];
        const int* in = sbin + rb * CAP;
        for (int k = lane; k < n; k += 64)
            atomicAdd(&h[in[k] - d0], 1);
    }
    __syncthreads();
    float* rs = rns_s + (size_t)rel * NN + d0;
    for (int i = t; i < nvalid; i += 1024)
        rs[i] = rsqrtf(fmaxf((float)h[i], 1.0f));
}

// ---------------------------------------------------------------------------
// Gather, all dst types merged (blockIdx.y = slot, blockIdx.z = dt) — r20
// proven config. 16 lanes x 16B per row; 8-deep edge batch; NT agg3 stores
// keep the 230MB write stream out of L3 (xb stays resident).
__global__ __launch_bounds__(256) void gather_kernel(const unsigned short* __restrict__ xb,
                                                     const int* __restrict__ csr,
                                                     const int* __restrict__ row_start,
                                                     const int* __restrict__ cnt_d,
                                                     const float* __restrict__ rns_s,
                                                     unsigned short* __restrict__ agg3) {
    const int slot = blockIdx.y;
    const int dt = blockIdx.z;
    const int rel = D_RELS[dt][slot];
    const unsigned short* x = xb + (size_t)D_SRC[rel] * NN * DD;
    const float* rs = rns_s + (size_t)rel * NN;

    int t = blockIdx.x * 256 + threadIdx.x;
    int node = t >> 4, lane = t & 15;
    if (node >= NN) return;
    int c = cnt_d[(size_t)rel * NN + node];
    const int4* bp4 = reinterpret_cast<const int4*>(csr + row_start[(size_t)rel * NN + node]);

    float acc[8];
#pragma unroll
    for (int j = 0; j < 8; ++j) acc[j] = 0.f;

    for (int e0 = 0; e0 < c; e0 += 8) {
        int4 b0 = bp4[e0 >> 2];
        int4 b1 = bp4[(e0 >> 2) + 1];
        int si[8] = {b0.x, b0.y, b0.z, b0.w, b1.x, b1.y, b1.z, b1.w};
        float ns[8];
        uint4 v[8];
#pragma unroll
        for (int u = 0; u < 8; ++u) {
            bool ok = (e0 + u < c);
            int s = ok ? si[u] : si[0];          // si[0] valid: loop entered => c > e0
            ns[u] = ok ? rs[s] : 0.0f;
            v[u] = *reinterpret_cast<const uint4*>(x + (size_t)s * DD + lane * 8);
        }
#pragma unroll
        for (int u = 0; u < 8; ++u) {
            float n = ns[u];
            unsigned w0 = v[u].x, w1 = v[u].y, w2 = v[u].z, w3 = v[u].w;
            acc[0] += __uint_as_float(w0 << 16) * n;
            acc[1] += __uint_as_float(w0 & 0xffff0000u) * n;
            acc[2] += __uint_as_float(w1 << 16) * n;
            acc[3] += __uint_as_float(w1 & 0xffff0000u) * n;
            acc[4] += __uint_as_float(w2 << 16) * n;
            acc[5] += __uint_as_float(w2 & 0xffff0000u) * n;
            acc[6] += __uint_as_float(w3 << 16) * n;
            acc[7] += __uint_as_float(w3 & 0xffff0000u) * n;
        }
    }
    float nd = rsqrtf(fmaxf((float)c, 1.0f));
    u32x4 o;
    o[0] = (unsigned)f2bf(acc[0] * nd) | ((unsigned)f2bf(acc[1] * nd) << 16);
    o[1] = (unsigned)f2bf(acc[2] * nd) | ((unsigned)f2bf(acc[3] * nd) << 16);
    o[2] = (unsigned)f2bf(acc[4] * nd) | ((unsigned)f2bf(acc[5] * nd) << 16);
    o[3] = (unsigned)f2bf(acc[6] * nd) | ((unsigned)f2bf(acc[7] * nd) << 16);
    __builtin_nontemporal_store(o, reinterpret_cast<u32x4*>(
        agg3 + ((size_t)dt * NN + node) * 384 + slot * 128 + lane * 8));
}

// ---------------------------------------------------------------------------
// Fused GEMM (r23-proven), all 3 dst types (blockIdx.y = dt). 128-row tile,
// 256 threads. A fragments direct from row-major agg3 (== fragment layout);
// W through LDS (issue-count amortization: one staged load feeds 64 MFMAs).
__global__ __launch_bounds__(256) void gemm_kernel(const unsigned short* __restrict__ agg3,
                                                   const unsigned short* __restrict__ Wt,
                                                   const float* __restrict__ bsum,
                                                   float* __restrict__ out) {
    __shared__ unsigned short Ws[128][72];   // 18.4 KB

    const int t = threadIdx.x;
    const int w = t >> 6;            // wave 0..3 -> rows w*32..+31
    const int lane = t & 63;
    const int row0 = blockIdx.x * 128;
    const int dt = blockIdx.y;
    const unsigned short* agg = agg3 + (size_t)dt * NN * 384;
    const int* rels = D_RELS[dt];

    // per-thread A fragment base pointers (rows clamped: OOB rows compute
    // garbage but are never stored by the guarded epilogue)
    const int ar0 = min(row0 + w * 32 + (lane & 15), NN - 1);
    const int ar1 = min(row0 + w * 32 + 16 + (lane & 15), NN - 1);
    const unsigned short* ap0 = agg + (size_t)ar0 * 384 + (lane >> 4) * 8;
    const unsigned short* ap1 = agg + (size_t)ar1 * 384 + (lane >> 4) * 8;

    f32x4 acc[2][8];
#pragma unroll
    for (int rg = 0; rg < 2; ++rg)
#pragma unroll
        for (int cg = 0; cg < 8; ++cg) acc[rg][cg] = (f32x4){0.f, 0.f, 0.f, 0.f};

    for (int c = 0; c < 6; ++c) {           // K chunks of 64
        __syncthreads();
        {   // stage W: 128 cols x 64 k of rel = rels[c>>1], k-half (c&1)
            int n = t & 127, koff = (t >> 7) * 32;
            int rel = rels[c >> 1];
            const uint4* p = reinterpret_cast<const uint4*>(
                Wt + (size_t)rel * 16384 + n * 128 + (c & 1) * 64 + koff);
            uint4* q = reinterpret_cast<uint4*>(&Ws[n][koff]);
            q[0] = p[0]; q[1] = p[1]; q[2] = p[2]; q[3] = p[3];
        }
        __syncthreads();
#pragma unroll
        for (int ks = 0; ks < 2; ++ks) {
            short8 a0 = *reinterpret_cast<const short8*>(ap0 + c * 64 + ks * 32);
            short8 a1 = *reinterpret_cast<const short8*>(ap1 + c * 64 + ks * 32);
#pragma unroll
            for (int cg = 0; cg < 8; ++cg) {
                short8 bfr = *reinterpret_cast<const short8*>(
                    &Ws[cg * 16 + (lane & 15)][ks * 32 + (lane >> 4) * 8]);
                acc[0][cg] = __builtin_amdgcn_mfma_f32_16x16x32_bf16(a0, bfr, acc[0][cg], 0, 0, 0);
                acc[1][cg] = __builtin_amdgcn_mfma_f32_16x16x32_bf16(a1, bfr, acc[1][cg], 0, 0, 0);
            }
        }
    }
    // epilogue: bias + ReLU, regular stores
    const int col = lane & 15;
    float* o = out + (size_t)dt * NN * DD;
#pragma unroll
    for (int rg = 0; rg < 2; ++rg) {
        const int rbase = row0 + w * 32 + rg * 16 + (lane >> 4) * 4;
#pragma unroll
        for (int cg = 0; cg < 8; ++cg) {
            float bs = bsum[dt * 128 + cg * 16 + col];
#pragma unroll
            for (int j = 0; j < 4; ++j) {
                int grow = rbase + j;
                if (grow < NN)
                    o[(size_t)grow * DD + cg * 16 + col] = fmaxf(acc[rg][cg][j] + bs, 0.f);
            }
        }
    }
}

// ---------------------------------------------------------------------------
extern "C" void kernel_launch(void* const* d_in, const int* in_sizes, int n_in,
                              void* d_out, int out_size, void* d_ws, size_t ws_size,
                              hipStream_t stream) {
    const float* x   = (const float*)d_in[0];   // [3, N, D]
    const float* W   = (const float*)d_in[1];   // [9, D, D]
    const float* b   = (const float*)d_in[2];   // [9, D]
    const int*   src = (const int*)d_in[3];     // [9, E]
    const int*   dst = (const int*)d_in[4];     // [9, E]
    float* out = (float*)d_out;                 // [3, N, D]

    // workspace layout (~460 MB of ~614 MB); every consumed region is fully
    // rewritten each call -> no memsets needed.
    unsigned short* xb   = (unsigned short*)d_ws;            // 3*NN*DD bf16   (76.8 MB)
    unsigned short* agg3 = xb + (size_t)3 * NN * DD;         // 3*NN*384 bf16  (230.4 MB)
    int*   csr    = (int*)(agg3 + (size_t)3 * NN * 384);     // 9*NBIN*RCAP int (35.9 MB)
    int*   row_start = csr + (size_t)9 * NBIN * RCAP;        // 9*NN int
    int*   cnt_d  = row_start + (size_t)9 * NN;              // 9*NN int
    float* rns_s  = (float*)(cnt_d + (size_t)9 * NN);        // 9*NN f32
    unsigned short* Wt = (unsigned short*)(rns_s + (size_t)9 * NN); // 9*16384 bf16
    float* bsum = (float*)(Wt + 9 * 16384);                  // 384 f32
    int*   dbin = (int*)(bsum + 384);                        // 9*WPR*NBIN*CAP int (52.6 MB)
    int*   sbin = dbin + (size_t)9 * WPR * NBIN * CAP;       // 9*WPR*NBIN*CAP int (52.6 MB)
    int*   dn   = sbin + (size_t)9 * WPR * NBIN * CAP;       // 9*WPR*NBIN int
    int*   sn   = dn + 9 * WPR * NBIN;                       // 9*WPR*NBIN int

    prep_kernel<<<(9 * 16384 + 255) / 256, 256, 0, stream>>>(W, b, Wt, bsum);
    part_kernel<<<dim3((WPR + 3) / 4, 9), 256, 0, stream>>>(src, dst, dbin, sbin, dn, sn);
    place_d_kernel<<<dim3(NBIN, 9), 1024, 0, stream>>>(dbin, dn, csr, row_start, cnt_d);
    place_s_kernel<<<dim3(NBIN, 9), 1024, 0, stream>>>(sbin, sn, rns_s);

    // xbf right before gather: xb enters gather L3-hot.
    xbf_kernel<<<(3 * NN * DD / 8 + 255) / 256, 256, 0, stream>>>(x, xb);

    dim3 gg((NN * 16 + 255) / 256, 3, 3);
    gather_kernel<<<gg, 256, 0, stream>>>(xb, csr, row_start, cnt_d, rns_s, agg3);

    dim3 mg((NN + 127) / 128, 3);
    gemm_kernel<<<mg, 256, 0, stream>>>(agg3, Wt, bsum, out);
}